// Round 13
// baseline (59.822 us; speedup 1.0000x reference)
//
#include <hip/hip_runtime.h>
#include <stdint.h>

// MaxSimLoss: anchor [256,64,128] f32, pos/neg [256,512,128] f32 -> scalar f32.
// R12 post-mortem: depth-2 rotation REGRESSED maxsim (74->87us profiled,
// scheduler went conservative); fusion mechanism itself proven correct.
// R13: decompose — exact R3 main loop (best measured: depth-1 ping-pong,
// 512 blocks, 108 VGPR) + R12's fused atomic-counter epilogue only.
// Six structural variants bracket maxsim at ~35us real (~4 TB/s mixed
// HBM/L3); this round removes the last tail launch from the best variant.

#define MARGIN_F 0.1f

typedef __attribute__((ext_vector_type(8))) short short8;   // 8 bf16
typedef __attribute__((ext_vector_type(4))) float floatx4;  // 4 f32 acc

// f32 -> bf16 round-to-nearest-even (inputs finite).
__device__ __forceinline__ unsigned short f2bf(float f) {
  union { float f; uint32_t u; } x; x.f = f;
  uint32_t u = x.u;
  return (unsigned short)((u + 0x7FFFu + ((u >> 16) & 1u)) >> 16);
}

__device__ __forceinline__ short8 pack8(float4 a, float4 b) {
  short8 r;
  r[0] = (short)f2bf(a.x); r[1] = (short)f2bf(a.y);
  r[2] = (short)f2bf(a.z); r[3] = (short)f2bf(a.w);
  r[4] = (short)f2bf(b.x); r[5] = (short)f2bf(b.y);
  r[6] = (short)f2bf(b.z); r[7] = (short)f2bf(b.w);
  return r;
}

__device__ __forceinline__ float sq4(float4 a) {
  return a.x * a.x + a.y * a.y + a.z * a.z + a.w * a.w;
}

// One block per (batch, side); 4 waves partition s (128 rows each, 8 chunks
// of 16 rows). Fragment pattern (verified R2/R3): lane holds row (lane&15),
// elements (lane>>4)*8 + k*32..+8 per k-slice; identical for A and B ->
// D = A.B^T with row(t) = (lane>>4)*4 + j, col(s) = lane&15.
__global__ __launch_bounds__(256, 2) void maxsim_kernel(
    const float* __restrict__ anchor, const float* __restrict__ pos,
    const float* __restrict__ neg, float* __restrict__ scores,
    int* __restrict__ counter, float* __restrict__ out) {
  __shared__ float sInvA[64];
  __shared__ float sPart[4][64];

  int bs = blockIdx.x;      // 0..511 = batch*2 + side
  int b = bs >> 1;
  int side = bs & 1;
  const float* base = (side ? neg : pos) + (size_t)b * 512 * 128;
  const float* abase = anchor + (size_t)b * 64 * 128;

  int tid = threadIdx.x;
  int lane = tid & 63;
  int wid = tid >> 6;  // 0..3
  int r = lane & 15;   // fragment row within subtile / accumulator col
  int g = lane >> 4;   // k-group (elements g*8 + k*32)

  const float* sbase = base + (size_t)wid * 128 * 128;

  // Issue chunk-0 s-loads FIRST so their latency hides under the anchor phase.
  float4 buf[2][8];  // fully unrolled chunk loop -> static indexing (rule #20)
  {
    const float* p = sbase + (size_t)r * 128 + g * 8;
#pragma unroll
    for (int k = 0; k < 4; ++k) {
      buf[0][2 * k] = *reinterpret_cast<const float4*>(p + k * 32);
      buf[0][2 * k + 1] = *reinterpret_cast<const float4*>(p + k * 32 + 4);
    }
  }

  // --- A: all 4 t-subtiles into registers, norms in-register. ---
  short8 aF[4][4];
#pragma unroll
  for (int tst = 0; tst < 4; ++tst) {
    const float* arow = abase + (size_t)(tst * 16 + r) * 128 + g * 8;
    float ssa[4];
#pragma unroll
    for (int k = 0; k < 4; ++k) {
      float4 v0 = *reinterpret_cast<const float4*>(arow + k * 32);
      float4 v1 = *reinterpret_cast<const float4*>(arow + k * 32 + 4);
      ssa[k] = sq4(v0) + sq4(v1);
      aF[tst][k] = pack8(v0, v1);
    }
    float ss = (ssa[0] + ssa[1]) + (ssa[2] + ssa[3]);  // tree, short chain
    ss += __shfl_xor(ss, 16);
    ss += __shfl_xor(ss, 32);
    if (g == 0) sInvA[tst * 16 + r] = 1.0f / fmaxf(sqrtf(ss), 1e-12f);
  }
  __syncthreads();  // sInvA ready; last sync until epilogue

  float rmax[4][4];
#pragma unroll
  for (int tst = 0; tst < 4; ++tst)
#pragma unroll
    for (int j = 0; j < 4; ++j) rmax[tst][j] = -1e30f;

#pragma unroll
  for (int i = 0; i < 8; ++i) {
    int cur = i & 1;
    if (i < 7) {
      const float* p = sbase + (size_t)((i + 1) * 16 + r) * 128 + g * 8;
#pragma unroll
      for (int k = 0; k < 4; ++k) {
        buf[cur ^ 1][2 * k] = *reinterpret_cast<const float4*>(p + k * 32);
        buf[cur ^ 1][2 * k + 1] =
            *reinterpret_cast<const float4*>(p + k * 32 + 4);
      }
    }
    // Row norm for this lane's loaded row (s = wid*128 + i*16 + r).
    float ss = ((sq4(buf[cur][0]) + sq4(buf[cur][1])) +
                (sq4(buf[cur][2]) + sq4(buf[cur][3]))) +
               ((sq4(buf[cur][4]) + sq4(buf[cur][5])) +
                (sq4(buf[cur][6]) + sq4(buf[cur][7])));
    ss += __shfl_xor(ss, 16);
    ss += __shfl_xor(ss, 32);
    float invb = 1.0f / fmaxf(sqrtf(ss), 1e-12f);

    short8 bF[4];
#pragma unroll
    for (int k = 0; k < 4; ++k)
      bF[k] = pack8(buf[cur][2 * k], buf[cur][2 * k + 1]);

    floatx4 acc[4] = {{0.f, 0.f, 0.f, 0.f},
                      {0.f, 0.f, 0.f, 0.f},
                      {0.f, 0.f, 0.f, 0.f},
                      {0.f, 0.f, 0.f, 0.f}};
#pragma unroll
    for (int k = 0; k < 4; ++k)
#pragma unroll
      for (int tst = 0; tst < 4; ++tst)
        acc[tst] = __builtin_amdgcn_mfma_f32_16x16x32_bf16(aF[tst][k], bF[k],
                                                           acc[tst], 0, 0, 0);
    // acc[tst][j]: row t = tst*16 + g*4 + j, col s-rel = lane&15.
    // invb for col r is this lane's own invb (it loaded row i*16 + r).
#pragma unroll
    for (int tst = 0; tst < 4; ++tst)
#pragma unroll
      for (int j = 0; j < 4; ++j)
        rmax[tst][j] = fmaxf(rmax[tst][j], acc[tst][j] * invb);
  }

  // Butterfly-max over cols (lane bits 0-3) -> per-t max over wave's s-range.
#pragma unroll
  for (int tst = 0; tst < 4; ++tst)
#pragma unroll
    for (int j = 0; j < 4; ++j) {
      float m = rmax[tst][j];
      m = fmaxf(m, __shfl_xor(m, 1));
      m = fmaxf(m, __shfl_xor(m, 2));
      m = fmaxf(m, __shfl_xor(m, 4));
      m = fmaxf(m, __shfl_xor(m, 8));
      rmax[tst][j] = m;  // t = tst*16 + g*4 + j, uniform over lane bits 0-3
    }
  if (r == 0) {
#pragma unroll
    for (int tst = 0; tst < 4; ++tst)
#pragma unroll
      for (int j = 0; j < 4; ++j)
        sPart[wid][tst * 16 + g * 4 + j] = rmax[tst][j];
  }
  __syncthreads();

  // Epilogue (wave 0): block score; last block computes hinge + mean inline.
  if (tid < 64) {
    float m = fmaxf(fmaxf(sPart[0][tid], sPart[1][tid]),
                    fmaxf(sPart[2][tid], sPart[3][tid]));
    float val = m * sInvA[tid];
#pragma unroll
    for (int mm = 1; mm < 64; mm <<= 1) val += __shfl_xor(val, mm);
    int lastflag = 0;
    if (tid == 0) {
      __hip_atomic_store(&scores[bs], val * (1.0f / 64.0f), __ATOMIC_RELEASE,
                         __HIP_MEMORY_SCOPE_AGENT);
      int prev = __hip_atomic_fetch_add(counter, 1, __ATOMIC_ACQ_REL,
                                        __HIP_MEMORY_SCOPE_AGENT);
      lastflag = (prev == 511);
    }
    lastflag = __shfl(lastflag, 0);
    if (lastflag) {
      // All 512 scores visible via the acq_rel counter chain. 4 batches/lane;
      // fixed summation order -> deterministic.
      float hsum = 0.f;
#pragma unroll
      for (int q = 0; q < 4; ++q) {
        int bb = tid * 4 + q;  // 0..255
        float p = __hip_atomic_load(&scores[2 * bb], __ATOMIC_RELAXED,
                                    __HIP_MEMORY_SCOPE_AGENT);
        float n = __hip_atomic_load(&scores[2 * bb + 1], __ATOMIC_RELAXED,
                                    __HIP_MEMORY_SCOPE_AGENT);
        hsum += fmaxf(MARGIN_F + n - p, 0.0f);
      }
#pragma unroll
      for (int mm = 1; mm < 64; mm <<= 1) hsum += __shfl_xor(hsum, mm);
      if (tid == 0) out[0] = hsum * (1.0f / 256.0f);
    }
  }
}

extern "C" void kernel_launch(void* const* d_in, const int* in_sizes, int n_in,
                              void* d_out, int out_size, void* d_ws,
                              size_t ws_size, hipStream_t stream) {
  const float* anchor = (const float*)d_in[0];
  const float* pos = (const float*)d_in[1];
  const float* neg = (const float*)d_in[2];
  float* scores = (float*)d_ws;           // 512 floats
  int* counter = (int*)((char*)d_ws + 512 * sizeof(float));
  // Zero the arrival counter each launch (capture-safe async memset).
  hipMemsetAsync(counter, 0, sizeof(int), stream);
  maxsim_kernel<<<dim3(512), dim3(256), 0, stream>>>(anchor, pos, neg, scores,
                                                     counter, (float*)d_out);
}